// Round 9
// baseline (442.311 us; speedup 1.0000x reference)
//
#include <hip/hip_runtime.h>

// out = noised + (2*STD) * noise, STD = 0.05  ->  out = a + 0.1f * b
// N = 64*3*512*512 = 50,331,648 fp32 (n4 = 12,582,912 float4s).
//
// History: R4 grid-stride 154us; R5 x4-unroll+nt 172us (bundle); R6
// exact-cover 1xfloat4/thread 141us (best); R7 2xfloat4/thread 147-150us
// (wave-churn refuted). FETCH shows input b L3-hits ~100%; HBM moves only
// 403MB (a-read + out-write) at 2.86 TB/s. This round isolates nt-store on
// the R6 structure: out is write-once/never-read, so skipping L3
// write-allocate frees L3 fill BW and protects b residency. Single-variable
// A/B vs R6: helps -> 125-135us; hurts -> nt refuted, R6 is the floor.

typedef float fx4 __attribute__((ext_vector_type(4)));

__global__ __launch_bounds__(256) void gaussian_noise_add_kernel(
    const fx4* __restrict__ a,
    const fx4* __restrict__ b,
    fx4* __restrict__ out,
    int n4)
{
    int i = blockIdx.x * blockDim.x + threadIdx.x;
    if (i < n4) {
        fx4 va = a[i];
        fx4 vb = b[i];
        fx4 vo = va + 0.1f * vb;
        __builtin_nontemporal_store(vo, &out[i]);
    }
}

// Scalar tail kernel (defensive; n is divisible by 4 for this problem).
__global__ void gaussian_noise_tail_kernel(
    const float* __restrict__ a,
    const float* __restrict__ b,
    float* __restrict__ out,
    int start, int n)
{
    int i = start + blockIdx.x * blockDim.x + threadIdx.x;
    if (i < n) out[i] = fmaf(0.1f, b[i], a[i]);
}

extern "C" void kernel_launch(void* const* d_in, const int* in_sizes, int n_in,
                              void* d_out, int out_size, void* d_ws, size_t ws_size,
                              hipStream_t stream)
{
    const float* a = (const float*)d_in[0];   // noised
    const float* b = (const float*)d_in[1];   // noise
    float* out = (float*)d_out;
    int n = out_size;
    int n4 = n / 4;

    const int block = 256;
    // Exact cover: one float4 per thread. n4 = 12,582,912 -> 49,152 blocks.
    int grid = (n4 + block - 1) / block;
    if (grid > 0) {
        gaussian_noise_add_kernel<<<grid, block, 0, stream>>>(
            (const fx4*)a, (const fx4*)b, (fx4*)out, n4);
    }

    int tail_start = n4 * 4;
    int tail = n - tail_start;
    if (tail > 0) {
        gaussian_noise_tail_kernel<<<(tail + block - 1) / block, block, 0, stream>>>(
            a, b, out, tail_start, n);
    }
}